// Round 12
// baseline (125.074 us; speedup 1.0000x reference)
//
#include <hip/hip_runtime.h>
#include <hip/hip_bf16.h>

typedef __bf16 bf16_t;
typedef __bf16 bf16x8 __attribute__((ext_vector_type(8)));
typedef float f32x4 __attribute__((ext_vector_type(4)));

#define FDIM 512
#define NTHR 512
#define BROWS 64    // 4 M-tiles x 16 rows
#define NBLK 2048   // 131072 / 64

// Kernel 1: Qt[g][f] = bf16(Q[f][g]) via LDS-tiled transpose
__global__ void qtrans_kernel(const float* __restrict__ Q, bf16_t* __restrict__ Qt) {
    __shared__ float t[32][33];
    int tx = threadIdx.x & 31;
    int ty = threadIdx.x >> 5;
    int f0 = blockIdx.x * 32;
    int g0 = blockIdx.y * 32;
#pragma unroll
    for (int i = 0; i < 4; ++i)
        t[ty + 8 * i][tx] = Q[(size_t)(f0 + ty + 8 * i) * FDIM + g0 + tx];
    __syncthreads();
#pragma unroll
    for (int i = 0; i < 4; ++i)
        Qt[(size_t)(g0 + ty + 8 * i) * FDIM + f0 + tx] = (bf16_t)t[tx][ty + 8 * i];
}

// Kernel 2: out[b] = sum_g (x Q)[b,g] * x[b,g]
// M-split + K-parity split: 8 waves = 4 M-tiles (16 rows each) x 2 K-parities.
// Wave (mt,kpar) holds a[8] (ks = 2i+kpar) = 32 VGPRs -> no spill possible.
// Partial rs per parity is exact by linearity; summed via LDS at the end.
// Qt panels (32 cols x 512k, triangle-trimmed) double-buffered in LDS,
// one barrier per panel. Epilogue dots vs fp32 x (L2-hot re-read).
__global__ __launch_bounds__(NTHR, 4) void bilinear_kernel(
    const float* __restrict__ x, const bf16_t* __restrict__ Qt,
    float* __restrict__ out)
{
    __shared__ bf16_t panel[2][32 * FDIM];   // 2 x 32 KB, swz: k ^= (c&15)<<3
    __shared__ float rsum[8][16];

    const int tid = threadIdx.x;
    const int w    = tid >> 6;
    const int l    = tid & 63;
    const int col  = l & 15;
    const int kg   = l >> 4;
    const int mt   = w >> 1;     // M-tile 0..3
    const int kpar = w & 1;      // K-step parity

    const int row0w = blockIdx.x * BROWS + mt * 16;   // wave's first row

    // ---- A: 8 k-frags (ks = 2i+kpar) into static regs (32 VGPRs) ----
    const float* arow = x + (size_t)(row0w + col) * FDIM + kg * 8;
    bf16x8 a[8];
#pragma unroll
    for (int i = 0; i < 8; ++i) {
        const int ks = 2 * i + kpar;
        float4 f0 = *(const float4*)(arow + ks * 32);
        float4 f1 = *(const float4*)(arow + ks * 32 + 4);
        bf16x8 v;
        v[0] = (bf16_t)f0.x; v[1] = (bf16_t)f0.y; v[2] = (bf16_t)f0.z; v[3] = (bf16_t)f0.w;
        v[4] = (bf16_t)f1.x; v[5] = (bf16_t)f1.y; v[6] = (bf16_t)f1.z; v[7] = (bf16_t)f1.w;
        a[i] = v;
        if ((i & 1) == 1) __builtin_amdgcn_sched_barrier(0);  // cap live float4s
    }

    // ---- stage panel 0 (cols 0..31, k < 32) ----
#pragma unroll
    for (int i = 0; i < 4; ++i) {
        int cc = i * 8 + w;
        if (l < 4) {
            bf16x8 q = *(const bf16x8*)(Qt + (size_t)cc * FDIM + l * 8);
            int e = cc * FDIM + ((l * 8) ^ ((cc & 15) << 3));
            *(bf16x8*)(&panel[0][0] + e) = q;
        }
    }
    __syncthreads();

    float rs[4] = {0.f, 0.f, 0.f, 0.f};

#pragma unroll 1
    for (int p = 0; p < 16; ++p) {
        const int buf = p & 1;
        const bf16_t* pb = &panel[buf][0];

        // ---- stage panel p+1 into buf^1 (triangle: k < 32*(p+2)) ----
        if (p + 1 < 16) {
            const int pn = p + 1;
            const int lim = 4 * (pn + 1);
            bf16_t* pw = &panel[buf ^ 1][0];
#pragma unroll
            for (int i = 0; i < 4; ++i) {
                int cc = i * 8 + w;
                if (l < lim) {
                    bf16x8 q = *(const bf16x8*)(Qt + (size_t)(pn * 32 + cc) * FDIM + l * 8);
                    int e = cc * FDIM + ((l * 8) ^ ((cc & 15) << 3));
                    *(bf16x8*)(pw + e) = q;
                }
            }
        }

        // ---- compute: this wave's parity K-steps, k <= 32*(p+1) ----
        f32x4 acc0, acc1;
#pragma unroll
        for (int j = 0; j < 4; ++j) { acc0[j] = 0.f; acc1[j] = 0.f; }

        const int kswz = col << 3;
#pragma unroll
        for (int i = 0; i < 8; ++i) {
            const int ks = 2 * i + kpar;
            if (ks <= p) {
                int kk = (ks * 32 + kg * 8) ^ kswz;
                bf16x8 b0 = *(const bf16x8*)(pb + col * FDIM + kk);
                bf16x8 b1 = *(const bf16x8*)(pb + (16 + col) * FDIM + kk);
                acc0 = __builtin_amdgcn_mfma_f32_16x16x32_bf16(a[i], b0, acc0, 0, 0, 0);
                acc1 = __builtin_amdgcn_mfma_f32_16x16x32_bf16(a[i], b1, acc1, 0, 0, 0);
            }
        }

        // ---- partial epilogue: rs += xQ_frag * x (fp32, L2-hot) ----
        const float* xe = x + (size_t)(row0w + kg * 4) * FDIM + p * 32 + col;
#pragma unroll
        for (int j = 0; j < 4; ++j) {
            rs[j] += acc0[j] * xe[(size_t)j * FDIM]
                   + acc1[j] * xe[(size_t)j * FDIM + 16];
        }

        __syncthreads();   // panel p+1 staged; panel p reads done
    }

    // ---- reduce over 16 cols (lanes sharing kg), publish, pair-sum ----
#pragma unroll
    for (int j = 0; j < 4; ++j) {
        float v2 = rs[j];
        v2 += __shfl_xor(v2, 1);
        v2 += __shfl_xor(v2, 2);
        v2 += __shfl_xor(v2, 4);
        v2 += __shfl_xor(v2, 8);
        rs[j] = v2;
    }
    if (col == 0) {
#pragma unroll
        for (int j = 0; j < 4; ++j)
            rsum[w][kg * 4 + j] = rs[j];
    }
    __syncthreads();

    if (tid < BROWS) {
        int mtile = tid >> 4;
        int i = tid & 15;
        out[(size_t)blockIdx.x * BROWS + mtile * 16 + i] =
            rsum[2 * mtile][i] + rsum[2 * mtile + 1][i];
    }
}

extern "C" void kernel_launch(void* const* d_in, const int* in_sizes, int n_in,
                              void* d_out, int out_size, void* d_ws, size_t ws_size,
                              hipStream_t stream) {
    const float* x = (const float*)d_in[0];
    const float* Q = (const float*)d_in[1];
    float* out = (float*)d_out;
    bf16_t* Qt = (bf16_t*)d_ws;        // 512*512*2 = 512 KB scratch

    dim3 tgrid(FDIM / 32, FDIM / 32);
    qtrans_kernel<<<tgrid, 256, 0, stream>>>(Q, Qt);
    bilinear_kernel<<<NBLK, NTHR, 0, stream>>>(x, Qt, out);
}